// Round 3
// baseline (266.953 us; speedup 1.0000x reference)
//
#include <hip/hip_runtime.h>

// Fusedmax: out = sparsemax(prox_TV1D(x, alpha=1)) row-wise. B=4096, N=512, fp32.
//
// v4: one wave per row, lane 0 runs Condat's scan (v2 proved lane-packing kills
// occupancy). Changes vs the 215us v3:
//  (a) DEFERRED FLUSH: jumps append (k0,end,value) segment records to an LDS
//      list instead of lane-0 serial ds_write flush loops; the whole wave
//      replays segments in parallel after the scan. row[] stays pristine during
//      the scan (matches the reference, which always reads original y) -> no
//      in-place hazard, no yLast special case. Chronological (ordered) replay
//      is used iff a rare end-phase "rewind" occurred (nk < k0), else parallel.
//  (b) 16-deep DOUBLE-BUFFERED batches with static position indexing: while
//      batch A is processed from registers, batch B's 16 ds_reads are in
//      flight. k = b + j (compile-time j) removes per-step k++/cnt++/end
//      checks; clamp count = di + j computed only when a clamp fires.
//  (c) jump handlers issue row[nk] + the next batch's loads before consuming
//      ynk -> one wait point per segment.
// Sparsemax (Michelot fixed point) and IO identical to the verified kernel.

#define TVN 512
#define LAMBDA 1.0f
#define NSEG_MAX 768

__device__ __forceinline__ float wave_reduce_sum(float v) {
#pragma unroll
    for (int off = 32; off > 0; off >>= 1) v += __shfl_xor(v, off, 64);
    return v;
}

#define LOAD16(P, B)                                                         \
    {                                                                        \
        const int _lb = (B);                                                 \
        P##0 = row[_lb + 0];   P##1 = row[_lb + 1];                          \
        P##2 = row[_lb + 2];   P##3 = row[_lb + 3];                          \
        P##4 = row[_lb + 4];   P##5 = row[_lb + 5];                          \
        P##6 = row[_lb + 6];   P##7 = row[_lb + 7];                          \
        P##8 = row[_lb + 8];   P##9 = row[_lb + 9];                          \
        P##10 = row[_lb + 10]; P##11 = row[_lb + 11];                        \
        P##12 = row[_lb + 12]; P##13 = row[_lb + 13];                        \
        P##14 = row[_lb + 14]; P##15 = row[_lb + 15];                        \
    }

// One Condat step at position k = b + J, consuming yn = row[b + J] (in W).
#define STEP(W, J)                                                           \
    {                                                                        \
        const float t1 = (W) + umin;                                         \
        if (t1 < vminl) goto neg_jump;                                       \
        const float t2 = (W) + umax;                                         \
        if (t2 > vmaxl) goto pos_jump;                                       \
        umin = t1 - vmin;                                                    \
        umax = t2 - vmax;                                                    \
        if (umin >= lam) {                                                   \
            const float e = (umin - lam) *                                   \
                            __builtin_amdgcn_rcpf((float)(di + (J)));        \
            vmin += e; vminl = vmin - lam; umin = lam; km = b + (J);         \
        }                                                                    \
        if (umax <= -lam) {                                                  \
            const float e = (umax + lam) *                                   \
                            __builtin_amdgcn_rcpf((float)(di + (J)));        \
            vmax += e; vmaxl = vmax + lam; umax = -lam; kp = b + (J);        \
        }                                                                    \
    }

#define STEP16(P)                                                            \
    STEP(P##0, 0)   STEP(P##1, 1)   STEP(P##2, 2)   STEP(P##3, 3)            \
    STEP(P##4, 4)   STEP(P##5, 5)   STEP(P##6, 6)   STEP(P##7, 7)            \
    STEP(P##8, 8)   STEP(P##9, 9)   STEP(P##10, 10) STEP(P##11, 11)          \
    STEP(P##12, 12) STEP(P##13, 13) STEP(P##14, 14) STEP(P##15, 15)

#define SETV_NEG()                                                           \
    vmin = ynk; vmax = ynk + twolam; umin = lam; umax = -lam;                 \
    vminl = vmin - lam; vmaxl = vmax + lam;

#define SETV_POS()                                                           \
    vmax = ynk; vmin = ynk - twolam; umin = lam; umax = -lam;                 \
    vminl = vmin - lam; vmaxl = vmax + lam;

__global__ __launch_bounds__(64) void fusedmax_kernel(const float* __restrict__ xin,
                                                      float* __restrict__ out) {
    __shared__ alignas(16) float row[TVN + 16];   // +16 pad: prefetch over-read only
    __shared__ int   segi[NSEG_MAX];              // (k0 << 16) | end
    __shared__ float segv[NSEG_MAX];
    __shared__ int nsS, rwS;

    const int t = threadIdx.x;                 // 0..63
    const long long r = blockIdx.x;
    const float lam = LAMBDA;

    // ---- stage row into LDS, coalesced (16B/lane) ----
    const float4* __restrict__ g4 = (const float4*)(xin + r * TVN);
    float4* s4 = (float4*)row;
    s4[t] = g4[t];
    s4[t + 64] = g4[t + 64];
    if (t < 16) row[TVN + t] = 0.0f;           // pad (loaded speculatively, never consumed)
    __syncthreads();

    // ---- Condat 1-D TV denoise, serial on lane 0, row stays PRISTINE ----
    if (t == 0) {
        const float twolam = 2.0f * lam;
        int k, k0, km, kp, b, di, ns, rewound, nk;
        float vmin, vmax, umin, umax, vminl, vmaxl, ynk;
        float wa0, wa1, wa2, wa3, wa4, wa5, wa6, wa7;
        float wa8, wa9, wa10, wa11, wa12, wa13, wa14, wa15;
        float wb0, wb1, wb2, wb3, wb4, wb5, wb6, wb7;
        float wb8, wb9, wb10, wb11, wb12, wb13, wb14, wb15;

        k = 0; k0 = 0; km = 0; kp = 0; ns = 0; rewound = 0;
        vmin = row[0] - lam; vmax = row[0] + lam;
        umin = lam; umax = -lam;
        vminl = vmin - lam; vmaxl = vmax + lam;
        goto refill;

    refill:                                    // generic re-entry: state current, k < TVN-1
        b = k + 1; di = k - k0 + 2;            // di = b - k0 + 1
        if (b > TVN - 17) goto tail;
        LOAD16(wa, b);
        goto fastA;

    fastA:                                     // wa holds row[b..b+15]
        LOAD16(wb, b + 16);                    // prefetch next batch
        STEP16(wa);
        b += 16; di += 16;
        if (b > TVN - 17) { k = b - 1; goto tail; }
        goto fastB;

    fastB:                                     // wb holds row[b..b+15]
        LOAD16(wa, b + 16);
        STEP16(wb);
        b += 16; di += 16;
        if (b > TVN - 17) { k = b - 1; goto tail; }
        goto fastA;

    neg_jump:
        segi[ns] = (k0 << 16) | km; segv[ns] = vmin; ++ns;
        nk = km + 1;
        if (nk < k0) rewound = 1;              // rewind (stale km after end-phase pos)
        if (nk > TVN - 1) nk = TVN - 1;
        ynk = row[nk];
        k = k0 = km = kp = nk;
        if (nk == TVN - 1) { SETV_NEG(); goto end_phase; }
        b = nk + 1; di = 2;
        if (b > TVN - 17) { SETV_NEG(); goto tail; }
        LOAD16(wa, b);                         // batch loads in flight with ynk
        SETV_NEG();
        goto fastA;

    pos_jump:
        segi[ns] = (k0 << 16) | kp; segv[ns] = vmax; ++ns;
        nk = kp + 1;
        if (nk < k0) rewound = 1;              // rewind (stale kp after end-phase neg)
        if (nk > TVN - 1) nk = TVN - 1;
        ynk = row[nk];
        k = k0 = km = kp = nk;
        if (nk == TVN - 1) { SETV_POS(); goto end_phase; }
        b = nk + 1; di = 2;
        if (b > TVN - 17) { SETV_POS(); goto tail; }
        LOAD16(wa, b);
        SETV_POS();
        goto fastA;

    tail:                                      // per-step with end checks; k <= TVN-2 on entry
        for (;;) {
            const float yn = row[k + 1];
            const float t1 = yn + umin;
            if (t1 < vminl) goto neg_jump;
            const float t2 = yn + umax;
            if (t2 > vmaxl) goto pos_jump;
            ++k;
            umin = t1 - vmin;
            umax = t2 - vmax;
            if (umin >= lam) {
                const float e = (umin - lam) * __builtin_amdgcn_rcpf((float)(k - k0 + 1));
                vmin += e; vminl = vmin - lam; umin = lam; km = k;
            }
            if (umax <= -lam) {
                const float e = (umax + lam) * __builtin_amdgcn_rcpf((float)(k - k0 + 1));
                vmax += e; vmaxl = vmax + lam; umax = -lam; kp = k;
            }
            if (k == TVN - 1) goto end_phase;
        }

    end_phase:                                 // k == TVN-1
        for (;;) {
            if (umin < 0.0f) {                 // end-phase negative jump
                segi[ns] = (k0 << 16) | km; segv[ns] = vmin; ++ns;
                nk = km + 1;
                if (nk < k0) rewound = 1;
                if (nk > TVN - 1) nk = TVN - 1;
                ynk = row[nk];                 // pristine row == reference's y
                k = k0 = km = nk;              // kp, vmax, vmaxl unchanged (reference)
                vmin = ynk; umin = lam; umax = ynk + lam - vmax;
                vminl = vmin - lam;
                if (k == TVN - 1) continue;
                goto refill;
            }
            if (umax > 0.0f) {                 // end-phase positive jump
                segi[ns] = (k0 << 16) | kp; segv[ns] = vmax; ++ns;
                nk = kp + 1;
                if (nk < k0) rewound = 1;
                if (nk > TVN - 1) nk = TVN - 1;
                ynk = row[nk];
                k = k0 = kp = nk;              // km, vmin, vminl unchanged (reference)
                vmax = ynk; umax = -lam; umin = ynk - lam - vmin;
                vmaxl = vmax + lam;
                if (k == TVN - 1) continue;
                goto refill;
            }
            {                                  // finish
                const float v = vmin + umin / (float)(k - k0 + 1);
                segi[ns] = (k0 << 16) | (TVN - 1); segv[ns] = v; ++ns;
                goto scan_done;
            }
        }

    scan_done:
        nsS = ns; rwS = rewound;
    }
    __syncthreads();

    // ---- segment replay: whole wave writes the TV result into row ----
    {
        const int n = nsS;
        if (rwS == 0) {
            // segments disjoint -> parallel: one lane per segment
            for (int s = t; s < n; s += 64) {
                const int pk = segi[s];
                const float v = segv[s];
                const int i1 = pk & 0xffff;
                for (int i = (pk >> 16); i <= i1; ++i) row[i] = v;
            }
        } else {
            // rare rewind -> chronological: wave-cooperative per segment, in order
            for (int s = 0; s < n; ++s) {
                const int pk = segi[s];
                const float v = segv[s];
                const int i1 = pk & 0xffff;
                for (int i = (pk >> 16) + t; i <= i1; i += 64) row[i] = v;
            }
        }
    }
    __syncthreads();

    // ---- sparsemax via Michelot fixed point (exact tau, no sort) ----
    float4 a = s4[t];
    float4 b = s4[t + 64];
    float v[8] = {a.x, a.y, a.z, a.w, b.x, b.y, b.z, b.w};

    float ls = v[0] + v[1] + v[2] + v[3] + v[4] + v[5] + v[6] + v[7];
    float S = wave_reduce_sum(ls);
    float tau = (S - 1.0f) * (1.0f / (float)TVN);   // support = all
    int cprev = TVN;
#pragma unroll 1
    for (int it = 0; it < 64; ++it) {
        float s = 0.0f, c = 0.0f;
#pragma unroll
        for (int j = 0; j < 8; ++j) {
            if (v[j] > tau) { s += v[j]; c += 1.0f; }
        }
        s = wave_reduce_sum(s);
        c = wave_reduce_sum(c);               // >= 1 always (tau < max)
        tau = (s - 1.0f) / c;
        int ci = (int)c;
        if (ci == cprev) break;               // support stabilized -> tau exact
        cprev = ci;
    }

    float4 oa, ob;
    oa.x = fmaxf(v[0] - tau, 0.0f);
    oa.y = fmaxf(v[1] - tau, 0.0f);
    oa.z = fmaxf(v[2] - tau, 0.0f);
    oa.w = fmaxf(v[3] - tau, 0.0f);
    ob.x = fmaxf(v[4] - tau, 0.0f);
    ob.y = fmaxf(v[5] - tau, 0.0f);
    ob.z = fmaxf(v[6] - tau, 0.0f);
    ob.w = fmaxf(v[7] - tau, 0.0f);
    float4* __restrict__ o4 = (float4*)(out + r * TVN);
    o4[t] = oa;
    o4[t + 64] = ob;
}

extern "C" void kernel_launch(void* const* d_in, const int* in_sizes, int n_in,
                              void* d_out, int out_size, void* d_ws, size_t ws_size,
                              hipStream_t stream) {
    const float* x = (const float*)d_in[0];
    float* out = (float*)d_out;
    const int rows = in_sizes[0] / TVN;       // 4096
    fusedmax_kernel<<<dim3(rows), dim3(64), 0, stream>>>(x, out);
}